// Round 3
// baseline (104.730 us; speedup 1.0000x reference)
//
#include <hip/hip_runtime.h>
#include <math.h>

#define NXC 432
#define NYC 496
#define CELLS (NYC * NXC)          // 214272
#define BATCH 4
#define PTOT 48000
#define NPT 32
#define EPSC 1e-3f
#define TCELLS 128                 // emit tile (CELLS % 128 == 0)

typedef float f2 __attribute__((ext_vector_type(2)));
typedef float f4v __attribute__((ext_vector_type(4)));

// ---------------------------------------------------------------------------
// Kernel 1: per-pillar fused PFN1 + PFN2 + BN + ReLU + max + attention mix.
// One wave per pillar; lane = output channel f. Inner loop packed fp32 pairs.
// LDS holds pillars feature-major: feats[8][32] per pillar.
// ---------------------------------------------------------------------------
__global__ __launch_bounds__(256) void pfe_kernel(
    const float* __restrict__ pillars, const float* __restrict__ w1,
    const float* __restrict__ bn1, const float* __restrict__ w2,
    const float* __restrict__ bn2, const float* __restrict__ wf1,
    const float* __restrict__ wf2, const float* __restrict__ fbn1,
    const float* __restrict__ fbn2, const int* __restrict__ coords,
    const int* __restrict__ num_points, float* __restrict__ comb,
    int* __restrict__ map)
{
    __shared__ float lds[4 * 256];   // 4 pillars x (8 feats x 32 pts), feature-major
    const int tid  = threadIdx.x;
    const int wave = tid >> 6;
    const int lane = tid & 63;
    const int pbase = blockIdx.x * 4;

    // cooperative transpose load: thread t loads one point's 4-feat chunk,
    // scatters to feature-major LDS. banks: addr%32 == point -> 2-way (free).
    {
        const float4 v = ((const float4*)(pillars + (size_t)pbase * 256))[tid];
        const int w  = tid >> 6;
        const int n  = (tid & 63) >> 1;
        const int c0 = (tid & 1) * 4;
        float* dst = lds + w * 256 + n;
        dst[(c0 + 0) * 32] = v.x;
        dst[(c0 + 1) * 32] = v.y;
        dst[(c0 + 2) * 32] = v.z;
        dst[(c0 + 3) * 32] = v.w;
    }
    __syncthreads();

    const int p = pbase + wave;
    const float* pl = lds + wave * 256;

    // mean xyz over all 32 points (reference does NOT mask), / num_points
    float sx = 0.f, sy = 0.f, sz = 0.f;
    if (lane < 32) {
        sx = pl[lane];
        sy = pl[32 + lane];
        sz = pl[64 + lane];
    }
#pragma unroll
    for (int off = 32; off; off >>= 1) {
        sx += __shfl_xor(sx, off);
        sy += __shfl_xor(sy, off);
        sz += __shfl_xor(sz, off);
    }
    const float inv_np = 1.0f / (float)num_points[p];
    const float mxm = sx * inv_np, mym = sy * inv_np, mzm = sz * inv_np;

    const int c1 = coords[p * 4 + 1], c2 = coords[p * 4 + 2], c3 = coords[p * 4 + 3];
    const float cx = c3 * 0.16f + 0.08f;
    const float cy = c2 * 0.16f + (-39.6f);
    const float cz = c1 * 4.0f  + (-1.0f);

    const int f = lane;

    // fold PFN1: h1 = x*AX + y*AY + z*AZ + i*AI + C0 (BN scale folded in)
    const float g1 = bn1[f], be1 = bn1[64 + f], bm1 = bn1[128 + f], bv1 = bn1[192 + f];
    const float s1 = g1 * rsqrtf(bv1 + EPSC);
    const float w10 = w1[f],        w11 = w1[64 + f],  w12 = w1[128 + f], w13 = w1[192 + f];
    const float w14 = w1[256 + f],  w15 = w1[320 + f], w16 = w1[384 + f];
    const float w17 = w1[448 + f],  w18 = w1[512 + f], w19 = w1[576 + f];
    const float AX = (w10 + w14 + w17) * s1;
    const float AY = (w11 + w15 + w18) * s1;
    const float AZ = (w12 + w16 + w19) * s1;
    const float AI = w13 * s1;
    const float C0 = be1 - bm1 * s1
                   - (mxm * w14 + mym * w15 + mzm * w16) * s1
                   - (cx * w17 + cy * w18 + cz * w19) * s1;

    // fold PFN2
    const float g2 = bn2[f], be2 = bn2[64 + f], bm2 = bn2[128 + f], bv2 = bn2[192 + f];
    const float s2 = g2 * rsqrtf(bv2 + EPSC);
    const float b0 = w2[f] * s2,        b1 = w2[64 + f] * s2;
    const float b2 = w2[128 + f] * s2,  b3 = w2[192 + f] * s2;
    const float b4 = w2[256 + f] * s2,  b5 = w2[320 + f] * s2;
    const float b6 = w2[384 + f] * s2,  b7 = w2[448 + f] * s2;
    const float C2 = be2 - bm2 * s2;

    // packed coefficient pairs
    const f2 AX2 = {AX, AX}, AY2 = {AY, AY}, AZ2 = {AZ, AZ}, AI2 = {AI, AI};
    const f2 B02 = {b0, b0}, B12 = {b1, b1}, B22 = {b2, b2}, B32 = {b3, b3};
    const f2 B42 = {b4, b4}, B52 = {b5, b5}, B62 = {b6, b6}, B72 = {b7, b7};
    const f2 C02 = {C0, C0}, C22 = {C2, C2};

    f2 m1 = {-1e30f, -1e30f}, m2 = {-1e30f, -1e30f};
#pragma unroll
    for (int k = 0; k < 8; k++) {
        const float4 X = *(const float4*)(pl + 0 * 32 + 4 * k);   // broadcast reads
        const float4 Y = *(const float4*)(pl + 1 * 32 + 4 * k);
        const float4 Z = *(const float4*)(pl + 2 * 32 + 4 * k);
        const float4 W = *(const float4*)(pl + 3 * 32 + 4 * k);
        const float4 Q4 = *(const float4*)(pl + 4 * 32 + 4 * k);
        const float4 Q5 = *(const float4*)(pl + 5 * 32 + 4 * k);
        const float4 Q6 = *(const float4*)(pl + 6 * 32 + 4 * k);
        const float4 Q7 = *(const float4*)(pl + 7 * 32 + 4 * k);

        const f2 xa = {X.x, X.y}, xb = {X.z, X.w};
        const f2 ya = {Y.x, Y.y}, yb = {Y.z, Y.w};
        const f2 za = {Z.x, Z.y}, zb = {Z.z, Z.w};
        const f2 wa = {W.x, W.y}, wb = {W.z, W.w};
        const f2 qa4 = {Q4.x, Q4.y}, qb4 = {Q4.z, Q4.w};
        const f2 qa5 = {Q5.x, Q5.y}, qb5 = {Q5.z, Q5.w};
        const f2 qa6 = {Q6.x, Q6.y}, qb6 = {Q6.z, Q6.w};
        const f2 qa7 = {Q7.x, Q7.y}, qb7 = {Q7.z, Q7.w};

        f2 h1a = xa * AX2 + C02;  h1a = ya * AY2 + h1a;
        h1a = za * AZ2 + h1a;     h1a = wa * AI2 + h1a;
        m1 = __builtin_elementwise_max(m1, h1a);
        f2 h1b = xb * AX2 + C02;  h1b = yb * AY2 + h1b;
        h1b = zb * AZ2 + h1b;     h1b = wb * AI2 + h1b;
        m1 = __builtin_elementwise_max(m1, h1b);

        f2 h2a = xa * B02 + C22;  h2a = ya * B12 + h2a;
        h2a = za * B22 + h2a;     h2a = wa * B32 + h2a;
        h2a = qa4 * B42 + h2a;    h2a = qa5 * B52 + h2a;
        h2a = qa6 * B62 + h2a;    h2a = qa7 * B72 + h2a;
        m2 = __builtin_elementwise_max(m2, h2a);
        f2 h2b = xb * B02 + C22;  h2b = yb * B12 + h2b;
        h2b = zb * B22 + h2b;     h2b = wb * B32 + h2b;
        h2b = qb4 * B42 + h2b;    h2b = qb5 * B52 + h2b;
        h2b = qb6 * B62 + h2b;    h2b = qb7 * B72 + h2b;
        m2 = __builtin_elementwise_max(m2, h2b);
    }
    const float f1v = fmaxf(fmaxf(m1.x, m1.y), 0.f);
    const float f2v = fmaxf(fmaxf(m2.x, m2.y), 0.f);

    // attention scalars
    float d1 = f1v * wf1[f];
    float d2 = f2v * wf2[f];
#pragma unroll
    for (int off = 32; off; off >>= 1) {
        d1 += __shfl_xor(d1, off);
        d2 += __shfl_xor(d2, off);
    }
    const float sc1 = (d1 - fbn1[2]) * (fbn1[0] * rsqrtf(fbn1[3] + EPSC)) + fbn1[1];
    const float sc2 = (d2 - fbn2[2]) * (fbn2[0] * rsqrtf(fbn2[3] + EPSC)) + fbn2[1];
    const float a0 = 1.0f / (1.0f + expf(sc2 - sc1));

    comb[p * 64 + f] = fmaf(f1v - f2v, a0, f2v);

    if (lane == 0) {
        const int lin  = c1 + c2 * NXC + c3;
        const int bidx = coords[p * 4 + 0];
        map[bidx * CELLS + lin] = p;
    }
}

// ---------------------------------------------------------------------------
// Kernel 2: dense emit via LDS transpose. 128 cells/block, float4 stores
// along cells -> 1 KB contiguous per store instruction, nontemporal.
// ---------------------------------------------------------------------------
__global__ __launch_bounds__(256) void emit_kernel(
    const int* __restrict__ map, const float* __restrict__ comb,
    float* __restrict__ out)
{
    __shared__ float lds[64 * 132];           // [ch][cell], pad 132 words
    const int t = threadIdx.x;
    const int gbase = blockIdx.x * TCELLS;    // global cell base (tile in one batch)

    // phase 1: gather comb rows -> LDS transposed
    {
        const int c = t >> 1;                 // cell within tile
        const int h = (t & 1) * 32;           // channel half
        const int m = map[gbase + c];
        const float sel = (m < 0) ? 0.f : 1.f;
        const float* src = comb + (size_t)((m < 0) ? 0 : m) * 64 + h;
        float* dst = lds + h * 132 + c;
#pragma unroll
        for (int j = 0; j < 8; j++) {
            const float4 v = *(const float4*)(src + j * 4);
            dst[(j * 4 + 0) * 132] = v.x * sel;
            dst[(j * 4 + 1) * 132] = v.y * sel;
            dst[(j * 4 + 2) * 132] = v.z * sel;
            dst[(j * 4 + 3) * 132] = v.w * sel;
        }
    }
    __syncthreads();

    // phase 2: coalesced float4 nontemporal stores, 2 channels per wave pass
    const int b = gbase / CELLS;
    const int L = gbase - b * CELLS;
    float* obase = out + (size_t)(b * 64) * CELLS + L;
#pragma unroll
    for (int r = 0; r < 8; r++) {
        const int idx = r * 256 + t;
        const int f = idx >> 5;               // channel
        const int g = idx & 31;               // float4 group along cells
        const f4v v = *(const f4v*)(lds + f * 132 + g * 4);
        __builtin_nontemporal_store(v, (f4v*)(obase + (size_t)f * CELLS + g * 4));
    }
}

extern "C" void kernel_launch(void* const* d_in, const int* in_sizes, int n_in,
                              void* d_out, int out_size, void* d_ws, size_t ws_size,
                              hipStream_t stream) {
    const float* pillars = (const float*)d_in[0];
    const float* w1      = (const float*)d_in[1];
    const float* bn1     = (const float*)d_in[2];
    const float* w2      = (const float*)d_in[3];
    const float* bn2     = (const float*)d_in[4];
    const float* wf1     = (const float*)d_in[5];
    const float* wf2     = (const float*)d_in[6];
    const float* fbn1    = (const float*)d_in[7];
    const float* fbn2    = (const float*)d_in[8];
    const int*   coords  = (const int*)d_in[9];
    const int*   nump    = (const int*)d_in[10];
    float* out = (float*)d_out;

    int*   map  = (int*)d_ws;
    float* comb = (float*)((char*)d_ws + (size_t)BATCH * CELLS * 4);

    (void)hipMemsetAsync(map, 0xFF, (size_t)BATCH * CELLS * 4, stream);  // all -1
    pfe_kernel<<<PTOT / 4, 256, 0, stream>>>(pillars, w1, bn1, w2, bn2,
                                             wf1, wf2, fbn1, fbn2,
                                             coords, nump, comb, map);
    emit_kernel<<<(BATCH * CELLS) / TCELLS, 256, 0, stream>>>(map, comb, out);
}

// Round 5
// 98.454 us; speedup vs baseline: 1.0637x; 1.0637x over previous
//
#include <hip/hip_runtime.h>
#include <math.h>

#define NXC 432
#define NYC 496
#define CELLS (NYC * NXC)          // 214272
#define BATCH 4
#define PTOT 48000
#define EPSC 1e-3f
#define TCELLS 128                 // emit tile (CELLS % 128 == 0)

typedef float f4v __attribute__((ext_vector_type(4)));

__device__ __forceinline__ float bcast_first(float x) {
    return __int_as_float(__builtin_amdgcn_readfirstlane(__float_as_int(x)));
}

// ---------------------------------------------------------------------------
// Kernel 1: per-pillar fused PFN1 + PFN2 + BN + ReLU + max + attention mix.
// One wave per pillar; lane = output channel f. Pillar data is wave-uniform:
// readfirstlane(p) makes all pillar/coord loads SCALAR (s_load via K$) --
// no LDS, no syncthreads, VALU consumes SGPR operands directly.
// ---------------------------------------------------------------------------
__global__ __launch_bounds__(256) void pfe_kernel(
    const float* __restrict__ pillars, const float* __restrict__ w1,
    const float* __restrict__ bn1, const float* __restrict__ w2,
    const float* __restrict__ bn2, const float* __restrict__ wf1,
    const float* __restrict__ wf2, const float* __restrict__ fbn1,
    const float* __restrict__ fbn2, const int* __restrict__ coords,
    const int* __restrict__ num_points, float* __restrict__ comb,
    int* __restrict__ map)
{
    const int tid  = threadIdx.x;
    const int lane = tid & 63;
    // wave-uniform pillar index (provably uniform for the compiler)
    const int p = __builtin_amdgcn_readfirstlane(blockIdx.x * 4 + (tid >> 6));
    const float* __restrict__ pl = pillars + (size_t)p * 256;

    // --- mean xyz over all 32 points (reference does NOT mask), / num_points
    // lanes 0..31 each load one point's first 4 feats, butterfly-reduce.
    float sx = 0.f, sy = 0.f, sz = 0.f;
    if (lane < 32) {
        const f4v v = *(const f4v*)(pl + lane * 8);
        sx = v.x; sy = v.y; sz = v.z;
    }
#pragma unroll
    for (int off = 16; off; off >>= 1) {
        sx += __shfl_xor(sx, off);
        sy += __shfl_xor(sy, off);
        sz += __shfl_xor(sz, off);
    }
    sx = bcast_first(sx); sy = bcast_first(sy); sz = bcast_first(sz);

    const float inv_np = 1.0f / (float)num_points[p];
    const float mxm = sx * inv_np, mym = sy * inv_np, mzm = sz * inv_np;

    const int c1 = coords[p * 4 + 1], c2 = coords[p * 4 + 2], c3 = coords[p * 4 + 3];
    const float cx = c3 * 0.16f + 0.08f;
    const float cy = c2 * 0.16f + (-39.6f);
    const float cz = c1 * 4.0f  + (-1.0f);

    const int f = lane;

    // fold PFN1: h1 = x*AX + y*AY + z*AZ + i*AI + C0 (BN scale folded in)
    const float g1 = bn1[f], be1 = bn1[64 + f], bm1 = bn1[128 + f], bv1 = bn1[192 + f];
    const float s1 = g1 * rsqrtf(bv1 + EPSC);
    const float w10 = w1[f],        w11 = w1[64 + f],  w12 = w1[128 + f], w13 = w1[192 + f];
    const float w14 = w1[256 + f],  w15 = w1[320 + f], w16 = w1[384 + f];
    const float w17 = w1[448 + f],  w18 = w1[512 + f], w19 = w1[576 + f];
    const float AX = (w10 + w14 + w17) * s1;
    const float AY = (w11 + w15 + w18) * s1;
    const float AZ = (w12 + w16 + w19) * s1;
    const float AI = w13 * s1;
    const float C0 = be1 - bm1 * s1
                   - (mxm * w14 + mym * w15 + mzm * w16) * s1
                   - (cx * w17 + cy * w18 + cz * w19) * s1;

    // fold PFN2
    const float g2 = bn2[f], be2 = bn2[64 + f], bm2 = bn2[128 + f], bv2 = bn2[192 + f];
    const float s2 = g2 * rsqrtf(bv2 + EPSC);
    const float b0 = w2[f] * s2,        b1 = w2[64 + f] * s2;
    const float b2 = w2[128 + f] * s2,  b3 = w2[192 + f] * s2;
    const float b4 = w2[256 + f] * s2,  b5 = w2[320 + f] * s2;
    const float b6 = w2[384 + f] * s2,  b7 = w2[448 + f] * s2;
    const float C2 = be2 - bm2 * s2;

    float max1 = -1e30f, max2 = -1e30f;
#pragma unroll
    for (int j = 0; j < 16; ++j) {
        // 2 points per 16-float chunk; uniform base + const offsets -> s_load
        float c[16];
#pragma unroll
        for (int k = 0; k < 16; ++k) c[k] = pl[j * 16 + k];

        const float h1a = fmaf(c[0], AX, fmaf(c[1], AY, fmaf(c[2], AZ, fmaf(c[3], AI, C0))));
        const float h1b = fmaf(c[8], AX, fmaf(c[9], AY, fmaf(c[10], AZ, fmaf(c[11], AI, C0))));
        const float h2a = fmaf(c[0], b0, fmaf(c[1], b1, fmaf(c[2], b2, fmaf(c[3], b3,
                          fmaf(c[4], b4, fmaf(c[5], b5, fmaf(c[6], b6, fmaf(c[7], b7, C2))))))));
        const float h2b = fmaf(c[8], b0, fmaf(c[9], b1, fmaf(c[10], b2, fmaf(c[11], b3,
                          fmaf(c[12], b4, fmaf(c[13], b5, fmaf(c[14], b6, fmaf(c[15], b7, C2))))))));
        max1 = fmaxf(max1, fmaxf(h1a, h1b));
        max2 = fmaxf(max2, fmaxf(h2a, h2b));
    }
    // relu(bn(h)).max(n) == max(0, max_n h')  (BN affine already folded)
    const float f1v = fmaxf(max1, 0.f);
    const float f2v = fmaxf(max2, 0.f);

    // attention scalars: s = bn(dot(f, wf))
    float d1 = f1v * wf1[f];
    float d2 = f2v * wf2[f];
#pragma unroll
    for (int off = 32; off; off >>= 1) {
        d1 += __shfl_xor(d1, off);
        d2 += __shfl_xor(d2, off);
    }
    const float sc1 = (d1 - fbn1[2]) * (fbn1[0] * rsqrtf(fbn1[3] + EPSC)) + fbn1[1];
    const float sc2 = (d2 - fbn2[2]) * (fbn2[0] * rsqrtf(fbn2[3] + EPSC)) + fbn2[1];
    const float a0 = 1.0f / (1.0f + expf(sc2 - sc1));   // softmax weight of branch 1

    comb[p * 64 + f] = fmaf(f1v - f2v, a0, f2v);        // f1*a0 + f2*(1-a0)

    if (lane == 0) {
        const int lin = c1 + c2 * NXC + c3;
        map[coords[p * 4 + 0] * CELLS + lin] = p;
    }
}

// ---------------------------------------------------------------------------
// Kernel 2: dense emit via LDS transpose. 128 cells/block, float4 stores
// along cells -> 1 KB contiguous per store instruction, nontemporal.
// ---------------------------------------------------------------------------
__global__ __launch_bounds__(256) void emit_kernel(
    const int* __restrict__ map, const float* __restrict__ comb,
    float* __restrict__ out)
{
    __shared__ float lds[64 * 132];           // [ch][cell], pad 132 words
    const int t = threadIdx.x;
    const int gbase = blockIdx.x * TCELLS;    // global cell base (tile in one batch)

    // phase 1: gather comb rows -> LDS transposed
    {
        const int c = t >> 1;                 // cell within tile
        const int h = (t & 1) * 32;           // channel half
        const int m = map[gbase + c];
        const float sel = (m < 0) ? 0.f : 1.f;
        const float* src = comb + (size_t)((m < 0) ? 0 : m) * 64 + h;
        float* dst = lds + h * 132 + c;
#pragma unroll
        for (int j = 0; j < 8; j++) {
            const float4 v = *(const float4*)(src + j * 4);
            dst[(j * 4 + 0) * 132] = v.x * sel;
            dst[(j * 4 + 1) * 132] = v.y * sel;
            dst[(j * 4 + 2) * 132] = v.z * sel;
            dst[(j * 4 + 3) * 132] = v.w * sel;
        }
    }
    __syncthreads();

    // phase 2: coalesced float4 nontemporal stores
    const int b = gbase / CELLS;
    const int L = gbase - b * CELLS;
    float* obase = out + (size_t)(b * 64) * CELLS + L;
#pragma unroll
    for (int r = 0; r < 8; r++) {
        const int idx = r * 256 + t;
        const int f = idx >> 5;               // channel
        const int g = idx & 31;               // float4 group along cells
        const f4v v = *(const f4v*)(lds + f * 132 + g * 4);
        __builtin_nontemporal_store(v, (f4v*)(obase + (size_t)f * CELLS + g * 4));
    }
}

extern "C" void kernel_launch(void* const* d_in, const int* in_sizes, int n_in,
                              void* d_out, int out_size, void* d_ws, size_t ws_size,
                              hipStream_t stream) {
    const float* pillars = (const float*)d_in[0];
    const float* w1      = (const float*)d_in[1];
    const float* bn1     = (const float*)d_in[2];
    const float* w2      = (const float*)d_in[3];
    const float* bn2     = (const float*)d_in[4];
    const float* wf1     = (const float*)d_in[5];
    const float* wf2     = (const float*)d_in[6];
    const float* fbn1    = (const float*)d_in[7];
    const float* fbn2    = (const float*)d_in[8];
    const int*   coords  = (const int*)d_in[9];
    const int*   nump    = (const int*)d_in[10];
    float* out = (float*)d_out;

    int*   map  = (int*)d_ws;
    float* comb = (float*)((char*)d_ws + (size_t)BATCH * CELLS * 4);

    (void)hipMemsetAsync(map, 0xFF, (size_t)BATCH * CELLS * 4, stream);  // all -1
    pfe_kernel<<<PTOT / 4, 256, 0, stream>>>(pillars, w1, bn1, w2, bn2,
                                             wf1, wf2, fbn1, fbn2,
                                             coords, nump, comb, map);
    emit_kernel<<<(BATCH * CELLS) / TCELLS, 256, 0, stream>>>(map, comb, out);
}